// Round 3
// baseline (21312.921 us; speedup 1.0000x reference)
//
#include <hip/hip_runtime.h>
#include <math.h>

#define EPSF 1e-5f

// DPP helper: v += value from lane (i - N) within the 16-lane DPP row (0 if OOB)
template<int CTRL>
__device__ __forceinline__ float dpp_add(float v) {
    int s = __builtin_amdgcn_update_dpp(0, __float_as_int(v), CTRL, 0xf, 0xf, true);
    return v + __int_as_float(s);
}

// ---------------- prep: weight transposes + bool-dtype detect ----------------
__global__ __launch_bounds__(256) void k_prep(
    const float* __restrict__ Wih,
    const float* __restrict__ W2, const float* __restrict__ W3,
    const unsigned char* __restrict__ fmask,
    float* __restrict__ WxT,
    float* __restrict__ W2T, float* __restrict__ W3T, int* __restrict__ flag)
{
    int idx = blockIdx.x * 256 + threadIdx.x;
    if (idx < 105984) {                 // Wih[768][138] x-part -> WxT[128][768]
        int j = idx / 138, k = idx % 138;
        if (k < 128) WxT[k * 768 + j] = Wih[idx];
    }
    if (idx < 409600) {                 // W[co][ci][5][5] -> WT[tap][ci][co]
        int co = idx / 3200, r = idx % 3200;
        int ci = r / 25, tap = r % 25;
        int dst = (tap * 128 + ci) * 128 + co;
        W2T[dst] = W2[idx];
        W3T[dst] = W3[idx];
    }
    if (idx == 0) {                     // bool stored as int32? bytes 1,2,3 of each word all zero
        int nz = 0;
        for (int i = 0; i < 4096; i++) if ((i & 3) != 0) nz |= fmask[i];
        *flag = nz ? 0 : 1;
    }
}

// ---------------- conv1: [32,1,1024,40] -> X1[b][t][m1(8)][co(128)] ----------------
__global__ __launch_bounds__(256) void k_conv1(
    const float* __restrict__ X, const float* __restrict__ W1,
    const float* __restrict__ bb, const float* __restrict__ gg,
    const float* __restrict__ be, const float* __restrict__ mm_,
    const float* __restrict__ vv, float* __restrict__ X1)
{
    __shared__ __align__(16) float xs[8][44];
    __shared__ __align__(16) float ws[25][128];
    __shared__ float sc[128], sh[128];
    int bid = blockIdx.x;
    int b = bid >> 8, t0 = (bid & 255) << 2;
    int tid = threadIdx.x;
    for (int e = tid; e < 8 * 44; e += 256) {
        int tt = e / 44, mm = e % 44;
        int gt = t0 + tt - 2, gm = mm - 2;
        float val = 0.f;
        if (gt >= 0 && gt < 1024 && gm >= 0 && gm < 40)
            val = X[(b * 1024 + gt) * 40 + gm];
        xs[tt][mm] = val;
    }
    for (int e = tid; e < 3200; e += 256) {
        int tap = e >> 7, co = e & 127;
        ws[tap][co] = W1[co * 25 + tap];
    }
    if (tid < 128) {
        float s = gg[tid] / sqrtf(vv[tid] + EPSF);
        sc[tid] = s;
        sh[tid] = (bb[tid] - mm_[tid]) * s + be[tid];
    }
    __syncthreads();
    int cog = tid >> 5;          // 8 groups x 16 co
    int m1i = (tid >> 2) & 7;    // pooled mel
    int tp  = tid & 3;           // t'
    int co0 = cog * 16;
    float val[5][16];
#pragma unroll
    for (int p = 0; p < 5; p++)
#pragma unroll
        for (int i = 0; i < 16; i++) val[p][i] = 0.f;
#pragma unroll
    for (int dt = 0; dt < 5; dt++) {
#pragma unroll
        for (int dm = 0; dm < 5; dm++) {
            float w[16];
#pragma unroll
            for (int i = 0; i < 16; i += 4)
                *(float4*)&w[i] = *(const float4*)&ws[dt * 5 + dm][co0 + i];
#pragma unroll
            for (int p = 0; p < 5; p++) {
                float x = xs[tp + dt][m1i * 5 + p + dm];
#pragma unroll
                for (int i = 0; i < 16; i++) val[p][i] = fmaf(x, w[i], val[p][i]);
            }
        }
    }
    float outv[16];
#pragma unroll
    for (int i = 0; i < 16; i++) {
        float s = sc[co0 + i], h = sh[co0 + i];
        float mx = 0.f;
#pragma unroll
        for (int p = 0; p < 5; p++) {
            float y = fmaf(val[p][i], s, h);
            y = fmaxf(y, 0.f);
            mx = fmaxf(mx, y);
        }
        outv[i] = mx;
    }
    float* dst = &X1[(((long)(b * 1024 + t0 + tp)) * 8 + m1i) * 128 + co0];
#pragma unroll
    for (int i = 0; i < 16; i += 4) *(float4*)&dst[i] = *(float4*)&outv[i];
}

// ---------------- conv2: X1 -> X2[b][t][m2(2)][co(128)] ----------------
__global__ __launch_bounds__(256) void k_conv2(
    const float* __restrict__ X1, const float* __restrict__ W2T,
    const float* __restrict__ bb, const float* __restrict__ gg,
    const float* __restrict__ be, const float* __restrict__ mm_,
    const float* __restrict__ vv, float* __restrict__ X2)
{
    __shared__ __align__(16) float xs[20][33][12];  // [t''][ci(pad)][m']
    __shared__ __align__(16) float ws[5][32][64];   // [dm][ci][co]
    __shared__ float sc[64], sh[64];
    int bid = blockIdx.x;
    int coh = bid & 1, t0 = ((bid >> 1) & 63) << 4, b = bid >> 7;
    int co_base = coh * 64;
    int tid = threadIdx.x;
    int tp = tid & 15, cog = tid >> 4;   // 16 t' x 16 cog(4 co each)
    if (tid < 64) {
        int co = co_base + tid;
        float s = gg[co] / sqrtf(vv[co] + EPSF);
        sc[tid] = s;
        sh[tid] = (bb[co] - mm_[co]) * s + be[co];
    }
    float acc[4][8];
#pragma unroll
    for (int c = 0; c < 4; c++)
#pragma unroll
        for (int m = 0; m < 8; m++) acc[c][m] = 0.f;

    for (int cc = 0; cc < 4; cc++) {
        __syncthreads();
        for (int e = tid; e < 20 * 32 * 12; e += 256) {
            int ci = e & 31, mm = (e >> 5) % 12, tt = e / 384;
            int gt = t0 + tt - 2, gm = mm - 2;
            float v = 0.f;
            if (gt >= 0 && gt < 1024 && gm >= 0 && gm < 8)
                v = X1[(((long)(b * 1024 + gt)) * 8 + gm) * 128 + cc * 32 + ci];
            xs[tt][ci][mm] = v;
        }
        for (int dt = 0; dt < 5; dt++) {
            __syncthreads();
            for (int e = tid; e < 5 * 32 * 64; e += 256) {
                int co = e & 63, ci = (e >> 6) & 31, dm = e >> 11;
                ws[dm][ci][co] = W2T[((dt * 5 + dm) * 128 + cc * 32 + ci) * 128 + co_base + co];
            }
            __syncthreads();
            for (int ci = 0; ci < 32; ci++) {
                float x[12];
                *(float4*)&x[0] = *(const float4*)&xs[tp + dt][ci][0];
                *(float4*)&x[4] = *(const float4*)&xs[tp + dt][ci][4];
                *(float4*)&x[8] = *(const float4*)&xs[tp + dt][ci][8];
#pragma unroll
                for (int dm = 0; dm < 5; dm++) {
                    float w[4];
                    *(float4*)&w[0] = *(const float4*)&ws[dm][ci][cog * 4];
#pragma unroll
                    for (int c = 0; c < 4; c++)
#pragma unroll
                        for (int m = 0; m < 8; m++)
                            acc[c][m] = fmaf(w[c], x[m + dm], acc[c][m]);
                }
            }
        }
    }
    int t = t0 + tp;
#pragma unroll
    for (int m2 = 0; m2 < 2; m2++) {
        float4 ov;
        float* po = (float*)&ov;
#pragma unroll
        for (int c = 0; c < 4; c++) {
            float s = sc[cog * 4 + c], h = sh[cog * 4 + c];
            float mx = 0.f;
#pragma unroll
            for (int q = 0; q < 4; q++) {
                float y = fmaf(acc[c][m2 * 4 + q], s, h);
                y = fmaxf(y, 0.f);
                mx = fmaxf(mx, y);
            }
            po[c] = mx;
        }
        *(float4*)&X2[(((long)(b * 1024 + t)) * 2 + m2) * 128 + co_base + cog * 4] = ov;
    }
}

// ---------------- conv3: X2 -> F[t][b][co] (mel pooled to 1) ----------------
__global__ __launch_bounds__(256) void k_conv3(
    const float* __restrict__ X2, const float* __restrict__ W3T,
    const float* __restrict__ bb, const float* __restrict__ gg,
    const float* __restrict__ be, const float* __restrict__ mm_,
    const float* __restrict__ vv, float* __restrict__ F)
{
    __shared__ __align__(16) float xs[20][33][8];   // [t''][ci(pad)][m'] (m' 0..5 used)
    __shared__ __align__(16) float ws[5][32][64];
    __shared__ float sc[64], sh[64];
    int bid = blockIdx.x;
    int coh = bid & 1, t0 = ((bid >> 1) & 63) << 4, b = bid >> 7;
    int co_base = coh * 64;
    int tid = threadIdx.x;
    int tp = tid & 15, cog = tid >> 4;
    if (tid < 64) {
        int co = co_base + tid;
        float s = gg[co] / sqrtf(vv[co] + EPSF);
        sc[tid] = s;
        sh[tid] = (bb[co] - mm_[co]) * s + be[co];
    }
    float acc[4][2];
#pragma unroll
    for (int c = 0; c < 4; c++) { acc[c][0] = 0.f; acc[c][1] = 0.f; }

    for (int cc = 0; cc < 4; cc++) {
        __syncthreads();
        for (int e = tid; e < 20 * 32 * 8; e += 256) {
            int ci = e & 31, mm = (e >> 5) & 7, tt = e >> 8;
            int gt = t0 + tt - 2, gm = mm - 2;
            float v = 0.f;
            if (gt >= 0 && gt < 1024 && (gm == 0 || gm == 1))
                v = X2[(((long)(b * 1024 + gt)) * 2 + gm) * 128 + cc * 32 + ci];
            xs[tt][ci][mm] = v;
        }
        for (int dt = 0; dt < 5; dt++) {
            __syncthreads();
            for (int e = tid; e < 5 * 32 * 64; e += 256) {
                int co = e & 63, ci = (e >> 6) & 31, dm = e >> 11;
                ws[dm][ci][co] = W3T[((dt * 5 + dm) * 128 + cc * 32 + ci) * 128 + co_base + co];
            }
            __syncthreads();
            for (int ci = 0; ci < 32; ci++) {
                float x[8];
                *(float4*)&x[0] = *(const float4*)&xs[tp + dt][ci][0];
                *(float4*)&x[4] = *(const float4*)&xs[tp + dt][ci][4];
#pragma unroll
                for (int dm = 0; dm < 5; dm++) {
                    float w[4];
                    *(float4*)&w[0] = *(const float4*)&ws[dm][ci][cog * 4];
#pragma unroll
                    for (int c = 0; c < 4; c++) {
                        acc[c][0] = fmaf(w[c], x[0 + dm], acc[c][0]);
                        acc[c][1] = fmaf(w[c], x[1 + dm], acc[c][1]);
                    }
                }
            }
        }
    }
    float4 ov;
    float* po = (float*)&ov;
#pragma unroll
    for (int c = 0; c < 4; c++) {
        float s = sc[cog * 4 + c], h = sh[cog * 4 + c];
        float y0 = fmaxf(fmaf(acc[c][0], s, h), 0.f);
        float y1 = fmaxf(fmaf(acc[c][1], s, h), 0.f);
        po[c] = fmaxf(y0, y1);
    }
    *(float4*)&F[((long)(t0 + tp) * 32 + b) * 128 + co_base + cog * 4] = ov;
}

// ---------------- Gx = F @ Wihx.T + bih : [32768,128]x[128,768] ----------------
__global__ __launch_bounds__(256) void k_gemm(
    const float* __restrict__ F, const float* __restrict__ WxT,
    const float* __restrict__ bih, float* __restrict__ Gx)
{
    __shared__ __align__(16) float Fs[64][33];
    __shared__ __align__(16) float Ws[32][256];
    int bid = blockIdx.x;
    int jt = bid % 3, tb0 = (bid / 3) * 64;
    int tid = threadIdx.x;
    int tx = tid & 31, ty = tid >> 5;
    float acc[8][8];
#pragma unroll
    for (int i = 0; i < 8; i++)
#pragma unroll
        for (int j = 0; j < 8; j++) acc[i][j] = 0.f;
    for (int cc = 0; cc < 4; cc++) {
        __syncthreads();
        for (int e = tid; e < 64 * 32; e += 256) {
            int ci = e & 31, i = e >> 5;
            Fs[i][ci] = F[(long)(tb0 + i) * 128 + cc * 32 + ci];
        }
        for (int e = tid; e < 32 * 256; e += 256) {
            int jj = e & 255, ci = e >> 8;
            Ws[ci][jj] = WxT[(cc * 32 + ci) * 768 + jt * 256 + jj];
        }
        __syncthreads();
        for (int ci = 0; ci < 32; ci++) {
            float a[8], w[8];
#pragma unroll
            for (int i = 0; i < 8; i++) a[i] = Fs[ty * 8 + i][ci];
            *(float4*)&w[0] = *(const float4*)&Ws[ci][tx * 8];
            *(float4*)&w[4] = *(const float4*)&Ws[ci][tx * 8 + 4];
#pragma unroll
            for (int i = 0; i < 8; i++)
#pragma unroll
                for (int j = 0; j < 8; j++) acc[i][j] = fmaf(a[i], w[j], acc[i][j]);
        }
    }
    float bj[8];
#pragma unroll
    for (int j = 0; j < 8; j++) bj[j] = bih[jt * 256 + tx * 8 + j];
#pragma unroll
    for (int i = 0; i < 8; i++) {
        float o[8];
#pragma unroll
        for (int j = 0; j < 8; j++) o[j] = acc[i][j] + bj[j];
        float* dst = &Gx[(long)(tb0 + ty * 8 + i) * 768 + jt * 256 + tx * 8];
        *(float4*)&dst[0] = *(float4*)&o[0];
        *(float4*)&dst[4] = *(float4*)&o[4];
    }
}

// ---------------- sequential GRU: 512 thr/batch, hybrid register+L2-stream Whh ----------
// Thread (rg=tid>>3, kgs=tid&7): register-resident rows rg*4+i (i<4) = rows [0,256)
// (128 weight VGPRs, fits 256-VGPR cap at launch_bounds(512,2)); rows [256,768)
// streamed from L2 each step (512 KB, XCD-L2-resident). h broadcast via 8
// bank-staggered LDS copies; tf/out projection weights in LDS. Per-row summation
// order identical to previous round -> bit-identical output.
__global__ __launch_bounds__(512, 2) void k_gru(
    const float* __restrict__ Whh, const float* __restrict__ Gx,
    const float* __restrict__ Wih, const float* __restrict__ bhh_g,
    const float* __restrict__ Wf, const float* __restrict__ bf_g,
    const float* __restrict__ targets, const unsigned char* __restrict__ fmask,
    const int* __restrict__ flag, float* __restrict__ out)
{
    __shared__ __align__(16) float hq[8 * 260];   // 8 staggered copies of h[256]
    __shared__ float gsum[768];
    __shared__ float tfl[16];
    __shared__ float wtfL[30 * 256];              // [g*10+c][j]
    __shared__ float WfL[2560];                   // [oc][256]
    const int b = blockIdx.x, tid = threadIdx.x;
    const int kgs = tid & 7, rg = tid >> 3;       // rg in [0,64)

    // register-resident Whh rows rg*4+i, cols kgs*32..+32
    float4 w4[4][8];
#pragma unroll
    for (int i = 0; i < 4; i++) {
        const float4* wr = (const float4*)&Whh[(rg * 4 + i) * 256 + kgs * 32];
#pragma unroll
        for (int q = 0; q < 8; q++) w4[i][q] = wr[q];
    }
    // streamed rows 256 + rg*8 + i, same col slice
    const float4* sp = (const float4*)&Whh[(256 + rg * 8) * 256 + kgs * 32];

    const bool isGate = (tid < 256);
    float bh0 = 0.f, bh1 = 0.f, bh2 = 0.f, hold = 0.f;
    if (isGate) { bh0 = bhh_g[tid]; bh1 = bhh_g[tid + 256]; bh2 = bhh_g[tid + 512]; }
    const bool isProj = (tid >= 256 && tid < 416);
    const int oc = (tid - 256) >> 4, seg = tid & 15;
    float bfc = isProj ? bf_g[oc] : 0.f;
    const bool isWr = isProj && (seg == 15);
    const int int32mode = flag[0];

    for (int e = tid; e < 7680; e += 512) {       // wtf -> LDS
        int cp = e >> 8, jj = e & 255;
        int g = cp / 10, c = cp - g * 10;
        wtfL[e] = Wih[(g * 256 + jj) * 138 + 128 + c];
    }
    for (int e = tid; e < 2560; e += 512) WfL[e] = Wf[e];
    for (int e = tid; e < 8 * 260; e += 512) hq[e] = 0.f;
    if (tid < 16) tfl[tid] = 0.f;
    __syncthreads();

    const float4* hbase = (const float4*)&hq[kgs * 292];  // kgs*260 + kgs*32

    for (int t = 0; t < 1024; t++) {
        // ---- prefetch (consumed after B1/B2) ----
        float gxr = 0.f, gxz = 0.f, gxn = 0.f;
        if (isGate) {
            const float* gx = &Gx[((long)t * 32 + b) * 768];
            gxr = gx[tid]; gxz = gx[tid + 256]; gxn = gx[tid + 512];
        }
        float tgt = 0.f; int fmv = 0;
        if (isWr) {
            tgt = targets[((long)b * 1024 + t) * 10 + oc];
            fmv = int32mode ? ((const int*)fmask)[t * 32 + b] : (int)fmask[t * 32 + b];
        }

        // ---- h fragments (LDS, conflict-free 8-way broadcast) ----
        float4 hv[8];
#pragma unroll
        for (int q = 0; q < 8; q++) hv[q] = hbase[q];

        // ---- register-resident rows ----
#pragma unroll
        for (int i = 0; i < 4; i++) {
            float s = 0.f;
#pragma unroll
            for (int q = 0; q < 8; q++) {
                s = fmaf(w4[i][q].x, hv[q].x, s);
                s = fmaf(w4[i][q].y, hv[q].y, s);
                s = fmaf(w4[i][q].z, hv[q].z, s);
                s = fmaf(w4[i][q].w, hv[q].w, s);
            }
            s = dpp_add<0x111>(s);
            s = dpp_add<0x112>(s);
            s = dpp_add<0x114>(s);
            if (kgs == 7) gsum[rg * 4 + i] = s;
        }

        // ---- streamed rows (L2-resident; unroll 1 bounds in-flight regs) ----
#pragma unroll 1
        for (int i = 0; i < 8; i++) {
            float4 sw[8];
#pragma unroll
            for (int q = 0; q < 8; q++) sw[q] = sp[i * 64 + q];
            float s = 0.f;
#pragma unroll
            for (int q = 0; q < 8; q++) {
                s = fmaf(sw[q].x, hv[q].x, s);
                s = fmaf(sw[q].y, hv[q].y, s);
                s = fmaf(sw[q].z, hv[q].z, s);
                s = fmaf(sw[q].w, hv[q].w, s);
            }
            s = dpp_add<0x111>(s);
            s = dpp_add<0x112>(s);
            s = dpp_add<0x114>(s);
            if (kgs == 7) gsum[256 + rg * 8 + i] = s;
        }
        __syncthreads();  // B1: gsum ready

        // ---- gate stage (threads 0..255): j = tid ----
        if (isGate) {
            float gr = gxr, gz = gxz, gn = gxn;
#pragma unroll
            for (int c = 0; c < 10; c++) {
                float tv = tfl[c];
                gr = fmaf(tv, wtfL[c * 256 + tid], gr);
                gz = fmaf(tv, wtfL[(10 + c) * 256 + tid], gz);
                gn = fmaf(tv, wtfL[(20 + c) * 256 + tid], gn);
            }
            float ar = gsum[tid] + bh0;
            float az = gsum[tid + 256] + bh1;
            float an = gsum[tid + 512] + bh2;
            float r = 1.0f / (1.0f + expf(-(gr + ar)));
            float z = 1.0f / (1.0f + expf(-(gz + az)));
            float n = tanhf(fmaf(r, an, gn));
            float hnew = (1.0f - z) * n + z * hold;
            hold = hnew;
#pragma unroll
            for (int c = 0; c < 8; c++) hq[c * 260 + tid] = hnew;
        }
        __syncthreads();  // B2: h ready

        // ---- out projection (threads 256..415) + tf update ----
        if (isProj) {
            const float* hp = &hq[(seg & 7) * 260 + seg * 16];
            const float* wfp = &WfL[oc * 256 + seg * 16];
            float s = 0.f;
#pragma unroll
            for (int i = 0; i < 16; i++) s = fmaf(wfp[i], hp[i], s);
            s = dpp_add<0x111>(s);
            s = dpp_add<0x112>(s);
            s = dpp_add<0x114>(s);
            s = dpp_add<0x118>(s);   // lane seg==15 holds full sum
            if (isWr) {
                float o = s + bfc;
                out[((long)b * 1024 + t) * 10 + oc] = o;
                float pred = (o > 0.f) ? 1.f : 0.f;
                tfl[oc] = fmv ? tgt : pred;
            }
        }
        // no 3rd barrier needed (see round-1 reasoning; tfl/gsum hazards separated by B1/B2)
    }
}

extern "C" void kernel_launch(void* const* d_in, const int* in_sizes, int n_in,
                              void* d_out, int out_size, void* d_ws, size_t ws_size,
                              hipStream_t stream) {
    (void)in_sizes; (void)n_in; (void)out_size; (void)ws_size;
    const float* features = (const float*)d_in[0];
    const float* targets  = (const float*)d_in[1];
    const unsigned char* fmask = (const unsigned char*)d_in[2];
    const float* W1  = (const float*)d_in[3];
    const float* b1  = (const float*)d_in[4];
    const float* g1  = (const float*)d_in[5];
    const float* be1 = (const float*)d_in[6];
    const float* m1  = (const float*)d_in[7];
    const float* v1  = (const float*)d_in[8];
    const float* W2  = (const float*)d_in[9];
    const float* b2  = (const float*)d_in[10];
    const float* g2  = (const float*)d_in[11];
    const float* be2 = (const float*)d_in[12];
    const float* m2  = (const float*)d_in[13];
    const float* v2  = (const float*)d_in[14];
    const float* W3  = (const float*)d_in[15];
    const float* b3  = (const float*)d_in[16];
    const float* g3  = (const float*)d_in[17];
    const float* be3 = (const float*)d_in[18];
    const float* m3  = (const float*)d_in[19];
    const float* v3  = (const float*)d_in[20];
    const float* Wih = (const float*)d_in[21];
    const float* Whh = (const float*)d_in[22];
    const float* bih = (const float*)d_in[23];
    const float* bhh = (const float*)d_in[24];
    const float* Wf  = (const float*)d_in[25];
    const float* bf  = (const float*)d_in[26];

    char* w = (char*)d_ws;
    float* WxT = (float*)(w + 786432);                  // 393216 B
    float* W2T = (float*)(w + 1179648);                 // 1638400 B
    float* W3T = (float*)(w + 2818048);                 // 1638400 B
    int*   flag = (int*)(w + 4456448);                  // 512 B slot
    float* X1  = (float*)(w + 4456960);                 // 128 MB; reused as Gx after conv2
    float* Gx  = X1;
    float* X2  = (float*)(w + 4456960 + 134217728);     // 32 MB
    float* F   = (float*)(w + 4456960 + 134217728 + 33554432); // 16 MB
    float* out = (float*)d_out;

    k_prep<<<1600, 256, 0, stream>>>(Wih, W2, W3, fmask, WxT, W2T, W3T, flag);
    k_conv1<<<8192, 256, 0, stream>>>(features, W1, b1, g1, be1, m1, v1, X1);
    k_conv2<<<4096, 256, 0, stream>>>(X1, W2T, b2, g2, be2, m2, v2, X2);
    k_conv3<<<4096, 256, 0, stream>>>(X2, W3T, b3, g3, be3, m3, v3, F);
    k_gemm<<<1536, 256, 0, stream>>>(F, WxT, bih, Gx);
    k_gru<<<32, 512, 0, stream>>>(Whh, Gx, Wih, bhh, Wf, bf, targets, fmask, flag, out);
}

// Round 4
// 18161.954 us; speedup vs baseline: 1.1735x; 1.1735x over previous
//
#include <hip/hip_runtime.h>
#include <math.h>

#define EPSF 1e-5f

// DPP helper: v += value from lane (i - N) within the 16-lane DPP row (0 if OOB)
template<int CTRL>
__device__ __forceinline__ float dpp_add(float v) {
    int s = __builtin_amdgcn_update_dpp(0, __float_as_int(v), CTRL, 0xf, 0xf, true);
    return v + __int_as_float(s);
}

// ---------------- prep: weight transposes + bool-dtype detect ----------------
__global__ __launch_bounds__(256) void k_prep(
    const float* __restrict__ Wih,
    const float* __restrict__ W2, const float* __restrict__ W3,
    const unsigned char* __restrict__ fmask,
    float* __restrict__ WxT,
    float* __restrict__ W2T, float* __restrict__ W3T, int* __restrict__ flag)
{
    int idx = blockIdx.x * 256 + threadIdx.x;
    if (idx < 105984) {                 // Wih[768][138] x-part -> WxT[128][768]
        int j = idx / 138, k = idx % 138;
        if (k < 128) WxT[k * 768 + j] = Wih[idx];
    }
    if (idx < 409600) {                 // W[co][ci][5][5] -> WT[tap][ci][co]
        int co = idx / 3200, r = idx % 3200;
        int ci = r / 25, tap = r % 25;
        int dst = (tap * 128 + ci) * 128 + co;
        W2T[dst] = W2[idx];
        W3T[dst] = W3[idx];
    }
    if (idx == 0) {                     // bool stored as int32? bytes 1,2,3 of each word all zero
        int nz = 0;
        for (int i = 0; i < 4096; i++) if ((i & 3) != 0) nz |= fmask[i];
        *flag = nz ? 0 : 1;
    }
}

// ---------------- conv1: [32,1,1024,40] -> X1[b][t][m1(8)][co(128)] ----------------
__global__ __launch_bounds__(256) void k_conv1(
    const float* __restrict__ X, const float* __restrict__ W1,
    const float* __restrict__ bb, const float* __restrict__ gg,
    const float* __restrict__ be, const float* __restrict__ mm_,
    const float* __restrict__ vv, float* __restrict__ X1)
{
    __shared__ __align__(16) float xs[8][44];
    __shared__ __align__(16) float ws[25][128];
    __shared__ float sc[128], sh[128];
    int bid = blockIdx.x;
    int b = bid >> 8, t0 = (bid & 255) << 2;
    int tid = threadIdx.x;
    for (int e = tid; e < 8 * 44; e += 256) {
        int tt = e / 44, mm = e % 44;
        int gt = t0 + tt - 2, gm = mm - 2;
        float val = 0.f;
        if (gt >= 0 && gt < 1024 && gm >= 0 && gm < 40)
            val = X[(b * 1024 + gt) * 40 + gm];
        xs[tt][mm] = val;
    }
    for (int e = tid; e < 3200; e += 256) {
        int tap = e >> 7, co = e & 127;
        ws[tap][co] = W1[co * 25 + tap];
    }
    if (tid < 128) {
        float s = gg[tid] / sqrtf(vv[tid] + EPSF);
        sc[tid] = s;
        sh[tid] = (bb[tid] - mm_[tid]) * s + be[tid];
    }
    __syncthreads();
    int cog = tid >> 5;          // 8 groups x 16 co
    int m1i = (tid >> 2) & 7;    // pooled mel
    int tp  = tid & 3;           // t'
    int co0 = cog * 16;
    float val[5][16];
#pragma unroll
    for (int p = 0; p < 5; p++)
#pragma unroll
        for (int i = 0; i < 16; i++) val[p][i] = 0.f;
#pragma unroll
    for (int dt = 0; dt < 5; dt++) {
#pragma unroll
        for (int dm = 0; dm < 5; dm++) {
            float w[16];
#pragma unroll
            for (int i = 0; i < 16; i += 4)
                *(float4*)&w[i] = *(const float4*)&ws[dt * 5 + dm][co0 + i];
#pragma unroll
            for (int p = 0; p < 5; p++) {
                float x = xs[tp + dt][m1i * 5 + p + dm];
#pragma unroll
                for (int i = 0; i < 16; i++) val[p][i] = fmaf(x, w[i], val[p][i]);
            }
        }
    }
    float outv[16];
#pragma unroll
    for (int i = 0; i < 16; i++) {
        float s = sc[co0 + i], h = sh[co0 + i];
        float mx = 0.f;
#pragma unroll
        for (int p = 0; p < 5; p++) {
            float y = fmaf(val[p][i], s, h);
            y = fmaxf(y, 0.f);
            mx = fmaxf(mx, y);
        }
        outv[i] = mx;
    }
    float* dst = &X1[(((long)(b * 1024 + t0 + tp)) * 8 + m1i) * 128 + co0];
#pragma unroll
    for (int i = 0; i < 16; i += 4) *(float4*)&dst[i] = *(float4*)&outv[i];
}

// ---------------- conv2: X1 -> X2[b][t][m2(2)][co(128)] ----------------
__global__ __launch_bounds__(256) void k_conv2(
    const float* __restrict__ X1, const float* __restrict__ W2T,
    const float* __restrict__ bb, const float* __restrict__ gg,
    const float* __restrict__ be, const float* __restrict__ mm_,
    const float* __restrict__ vv, float* __restrict__ X2)
{
    __shared__ __align__(16) float xs[20][33][12];  // [t''][ci(pad)][m']
    __shared__ __align__(16) float ws[5][32][64];   // [dm][ci][co]
    __shared__ float sc[64], sh[64];
    int bid = blockIdx.x;
    int coh = bid & 1, t0 = ((bid >> 1) & 63) << 4, b = bid >> 7;
    int co_base = coh * 64;
    int tid = threadIdx.x;
    int tp = tid & 15, cog = tid >> 4;   // 16 t' x 16 cog(4 co each)
    if (tid < 64) {
        int co = co_base + tid;
        float s = gg[co] / sqrtf(vv[co] + EPSF);
        sc[tid] = s;
        sh[tid] = (bb[co] - mm_[co]) * s + be[co];
    }
    float acc[4][8];
#pragma unroll
    for (int c = 0; c < 4; c++)
#pragma unroll
        for (int m = 0; m < 8; m++) acc[c][m] = 0.f;

    for (int cc = 0; cc < 4; cc++) {
        __syncthreads();
        for (int e = tid; e < 20 * 32 * 12; e += 256) {
            int ci = e & 31, mm = (e >> 5) % 12, tt = e / 384;
            int gt = t0 + tt - 2, gm = mm - 2;
            float v = 0.f;
            if (gt >= 0 && gt < 1024 && gm >= 0 && gm < 8)
                v = X1[(((long)(b * 1024 + gt)) * 8 + gm) * 128 + cc * 32 + ci];
            xs[tt][ci][mm] = v;
        }
        for (int dt = 0; dt < 5; dt++) {
            __syncthreads();
            for (int e = tid; e < 5 * 32 * 64; e += 256) {
                int co = e & 63, ci = (e >> 6) & 31, dm = e >> 11;
                ws[dm][ci][co] = W2T[((dt * 5 + dm) * 128 + cc * 32 + ci) * 128 + co_base + co];
            }
            __syncthreads();
            for (int ci = 0; ci < 32; ci++) {
                float x[12];
                *(float4*)&x[0] = *(const float4*)&xs[tp + dt][ci][0];
                *(float4*)&x[4] = *(const float4*)&xs[tp + dt][ci][4];
                *(float4*)&x[8] = *(const float4*)&xs[tp + dt][ci][8];
#pragma unroll
                for (int dm = 0; dm < 5; dm++) {
                    float w[4];
                    *(float4*)&w[0] = *(const float4*)&ws[dm][ci][cog * 4];
#pragma unroll
                    for (int c = 0; c < 4; c++)
#pragma unroll
                        for (int m = 0; m < 8; m++)
                            acc[c][m] = fmaf(w[c], x[m + dm], acc[c][m]);
                }
            }
        }
    }
    int t = t0 + tp;
#pragma unroll
    for (int m2 = 0; m2 < 2; m2++) {
        float4 ov;
        float* po = (float*)&ov;
#pragma unroll
        for (int c = 0; c < 4; c++) {
            float s = sc[cog * 4 + c], h = sh[cog * 4 + c];
            float mx = 0.f;
#pragma unroll
            for (int q = 0; q < 4; q++) {
                float y = fmaf(acc[c][m2 * 4 + q], s, h);
                y = fmaxf(y, 0.f);
                mx = fmaxf(mx, y);
            }
            po[c] = mx;
        }
        *(float4*)&X2[(((long)(b * 1024 + t)) * 2 + m2) * 128 + co_base + cog * 4] = ov;
    }
}

// ---------------- conv3: X2 -> F[t][b][co] (mel pooled to 1) ----------------
__global__ __launch_bounds__(256) void k_conv3(
    const float* __restrict__ X2, const float* __restrict__ W3T,
    const float* __restrict__ bb, const float* __restrict__ gg,
    const float* __restrict__ be, const float* __restrict__ mm_,
    const float* __restrict__ vv, float* __restrict__ F)
{
    __shared__ __align__(16) float xs[20][33][8];   // [t''][ci(pad)][m'] (m' 0..5 used)
    __shared__ __align__(16) float ws[5][32][64];
    __shared__ float sc[64], sh[64];
    int bid = blockIdx.x;
    int coh = bid & 1, t0 = ((bid >> 1) & 63) << 4, b = bid >> 7;
    int co_base = coh * 64;
    int tid = threadIdx.x;
    int tp = tid & 15, cog = tid >> 4;
    if (tid < 64) {
        int co = co_base + tid;
        float s = gg[co] / sqrtf(vv[co] + EPSF);
        sc[tid] = s;
        sh[tid] = (bb[co] - mm_[co]) * s + be[co];
    }
    float acc[4][2];
#pragma unroll
    for (int c = 0; c < 4; c++) { acc[c][0] = 0.f; acc[c][1] = 0.f; }

    for (int cc = 0; cc < 4; cc++) {
        __syncthreads();
        for (int e = tid; e < 20 * 32 * 8; e += 256) {
            int ci = e & 31, mm = (e >> 5) & 7, tt = e >> 8;
            int gt = t0 + tt - 2, gm = mm - 2;
            float v = 0.f;
            if (gt >= 0 && gt < 1024 && (gm == 0 || gm == 1))
                v = X2[(((long)(b * 1024 + gt)) * 2 + gm) * 128 + cc * 32 + ci];
            xs[tt][ci][mm] = v;
        }
        for (int dt = 0; dt < 5; dt++) {
            __syncthreads();
            for (int e = tid; e < 5 * 32 * 64; e += 256) {
                int co = e & 63, ci = (e >> 6) & 31, dm = e >> 11;
                ws[dm][ci][co] = W3T[((dt * 5 + dm) * 128 + cc * 32 + ci) * 128 + co_base + co];
            }
            __syncthreads();
            for (int ci = 0; ci < 32; ci++) {
                float x[8];
                *(float4*)&x[0] = *(const float4*)&xs[tp + dt][ci][0];
                *(float4*)&x[4] = *(const float4*)&xs[tp + dt][ci][4];
#pragma unroll
                for (int dm = 0; dm < 5; dm++) {
                    float w[4];
                    *(float4*)&w[0] = *(const float4*)&ws[dm][ci][cog * 4];
#pragma unroll
                    for (int c = 0; c < 4; c++) {
                        acc[c][0] = fmaf(w[c], x[0 + dm], acc[c][0]);
                        acc[c][1] = fmaf(w[c], x[1 + dm], acc[c][1]);
                    }
                }
            }
        }
    }
    float4 ov;
    float* po = (float*)&ov;
#pragma unroll
    for (int c = 0; c < 4; c++) {
        float s = sc[cog * 4 + c], h = sh[cog * 4 + c];
        float y0 = fmaxf(fmaf(acc[c][0], s, h), 0.f);
        float y1 = fmaxf(fmaf(acc[c][1], s, h), 0.f);
        po[c] = fmaxf(y0, y1);
    }
    *(float4*)&F[((long)(t0 + tp) * 32 + b) * 128 + co_base + cog * 4] = ov;
}

// ---------------- Gx = F @ Wihx.T + bih : [32768,128]x[128,768] ----------------
__global__ __launch_bounds__(256) void k_gemm(
    const float* __restrict__ F, const float* __restrict__ WxT,
    const float* __restrict__ bih, float* __restrict__ Gx)
{
    __shared__ __align__(16) float Fs[64][33];
    __shared__ __align__(16) float Ws[32][256];
    int bid = blockIdx.x;
    int jt = bid % 3, tb0 = (bid / 3) * 64;
    int tid = threadIdx.x;
    int tx = tid & 31, ty = tid >> 5;
    float acc[8][8];
#pragma unroll
    for (int i = 0; i < 8; i++)
#pragma unroll
        for (int j = 0; j < 8; j++) acc[i][j] = 0.f;
    for (int cc = 0; cc < 4; cc++) {
        __syncthreads();
        for (int e = tid; e < 64 * 32; e += 256) {
            int ci = e & 31, i = e >> 5;
            Fs[i][ci] = F[(long)(tb0 + i) * 128 + cc * 32 + ci];
        }
        for (int e = tid; e < 32 * 256; e += 256) {
            int jj = e & 255, ci = e >> 8;
            Ws[ci][jj] = WxT[(cc * 32 + ci) * 768 + jt * 256 + jj];
        }
        __syncthreads();
        for (int ci = 0; ci < 32; ci++) {
            float a[8], w[8];
#pragma unroll
            for (int i = 0; i < 8; i++) a[i] = Fs[ty * 8 + i][ci];
            *(float4*)&w[0] = *(const float4*)&Ws[ci][tx * 8];
            *(float4*)&w[4] = *(const float4*)&Ws[ci][tx * 8 + 4];
#pragma unroll
            for (int i = 0; i < 8; i++)
#pragma unroll
                for (int j = 0; j < 8; j++) acc[i][j] = fmaf(a[i], w[j], acc[i][j]);
        }
    }
    float bj[8];
#pragma unroll
    for (int j = 0; j < 8; j++) bj[j] = bih[jt * 256 + tx * 8 + j];
#pragma unroll
    for (int i = 0; i < 8; i++) {
        float o[8];
#pragma unroll
        for (int j = 0; j < 8; j++) o[j] = acc[i][j] + bj[j];
        float* dst = &Gx[(long)(tb0 + ty * 8 + i) * 768 + jt * 256 + tx * 8];
        *(float4*)&dst[0] = *(float4*)&o[0];
        *(float4*)&dst[4] = *(float4*)&o[4];
    }
}

// ---------------- sequential GRU: 512 thr/batch, waves_per_eu pinned to (2,2) ------------
// amdgpu_waves_per_eu(2,2): exactly 2 waves/EU (one 512-thr WG per CU) => 256-VGPR budget,
// removing the compiler's incentive to spill/remat for higher occupancy (R2/R3 failure).
// Thread (rg=tid>>3, kgs=tid&7): 3 pinned rows (rg*3+i, rows 0..191; 96 VGPRs) +
// 9 streamed rows (192+rg*9+i, rows 192..767) via depth-3 rotating float4 buffer (96 VGPRs).
// h broadcast from 8 bank-staggered LDS copies; tf/out-proj weights in LDS (off reg budget).
// Row dot order (k ascending per 32-slice, DPP tree) identical to prior rounds.
__global__ __attribute__((amdgpu_waves_per_eu(2, 2))) __launch_bounds__(512) void k_gru(
    const float* __restrict__ Whh, const float* __restrict__ Gx,
    const float* __restrict__ Wih, const float* __restrict__ bhh_g,
    const float* __restrict__ Wf, const float* __restrict__ bf_g,
    const float* __restrict__ targets, const unsigned char* __restrict__ fmask,
    const int* __restrict__ flag, float* __restrict__ out)
{
    __shared__ __align__(16) float hq[8 * 260];   // 8 staggered copies of h[256]
    __shared__ float gsum[768];
    __shared__ float tfl[16];
    __shared__ float wtfL[30 * 256];              // [g*10+c][j]
    __shared__ float WfL[2560];                   // [oc][256]
    const int b = blockIdx.x, tid = threadIdx.x;
    const int kgs = tid & 7, rg = tid >> 3;       // rg in [0,64)

    // pinned Whh rows rg*3+i (i<3), cols kgs*32..+32  -> 96 VGPRs
    float4 w4[3][8];
#pragma unroll
    for (int i = 0; i < 3; i++) {
        const float4* wr = (const float4*)&Whh[(rg * 3 + i) * 256 + kgs * 32];
#pragma unroll
        for (int q = 0; q < 8; q++) w4[i][q] = wr[q];
    }
    // streamed rows 192 + rg*9 + i (i<9), same col slice
    const float4* spr = (const float4*)&Whh[(192 + rg * 9) * 256 + kgs * 32];

    const bool isGate = (tid < 256);
    float bh0 = 0.f, bh1 = 0.f, bh2 = 0.f, hold = 0.f;
    if (isGate) { bh0 = bhh_g[tid]; bh1 = bhh_g[tid + 256]; bh2 = bhh_g[tid + 512]; }
    const bool isProj = (tid >= 256 && tid < 416);
    const int oc = (tid - 256) >> 4, seg = tid & 15;
    float bfc = isProj ? bf_g[oc] : 0.f;
    const bool isWr = isProj && (seg == 15);
    const int int32mode = flag[0];

    for (int e = tid; e < 7680; e += 512) {       // wtf -> LDS
        int cp = e >> 8, jj = e & 255;
        int g = cp / 10, c = cp - g * 10;
        wtfL[e] = Wih[(g * 256 + jj) * 138 + 128 + c];
    }
    for (int e = tid; e < 2560; e += 512) WfL[e] = Wf[e];
    for (int e = tid; e < 8 * 260; e += 512) hq[e] = 0.f;
    if (tid < 16) tfl[tid] = 0.f;
    __syncthreads();

    const float4* hbase = (const float4*)&hq[kgs * 292];  // kgs*260 + kgs*32

    for (int t = 0; t < 1024; t++) {
        // ---- issue stream rows 0..2 first (latency covered by pinned compute) ----
        float4 sb[3][8];
#pragma unroll
        for (int p = 0; p < 3; p++)
#pragma unroll
            for (int q = 0; q < 8; q++) sb[p][q] = spr[p * 64 + q];

        // ---- prefetch step inputs (consumed after B1/B2) ----
        float gxr = 0.f, gxz = 0.f, gxn = 0.f;
        if (isGate) {
            const float* gx = &Gx[((long)t * 32 + b) * 768];
            gxr = gx[tid]; gxz = gx[tid + 256]; gxn = gx[tid + 512];
        }
        float tgt = 0.f; int fmv = 0;
        if (isWr) {
            tgt = targets[((long)b * 1024 + t) * 10 + oc];
            fmv = int32mode ? ((const int*)fmask)[t * 32 + b] : (int)fmask[t * 32 + b];
        }

        // ---- h fragments (LDS, conflict-free 8-way broadcast) ----
        float4 hv[8];
#pragma unroll
        for (int q = 0; q < 8; q++) hv[q] = hbase[q];

        // ---- pinned rows (pure VALU; overlaps stream arrival) ----
#pragma unroll
        for (int i = 0; i < 3; i++) {
            float s = 0.f;
#pragma unroll
            for (int q = 0; q < 8; q++) {
                s = fmaf(w4[i][q].x, hv[q].x, s);
                s = fmaf(w4[i][q].y, hv[q].y, s);
                s = fmaf(w4[i][q].z, hv[q].z, s);
                s = fmaf(w4[i][q].w, hv[q].w, s);
            }
            s = dpp_add<0x111>(s);
            s = dpp_add<0x112>(s);
            s = dpp_add<0x114>(s);
            if (kgs == 7) gsum[rg * 3 + i] = s;
        }

        // ---- streamed rows, depth-3 rotation ----
#pragma unroll
        for (int i = 0; i < 9; i++) {
            const int sl = i % 3;
            float s = 0.f;
#pragma unroll
            for (int q = 0; q < 8; q++) {
                s = fmaf(sb[sl][q].x, hv[q].x, s);
                s = fmaf(sb[sl][q].y, hv[q].y, s);
                s = fmaf(sb[sl][q].z, hv[q].z, s);
                s = fmaf(sb[sl][q].w, hv[q].w, s);
            }
            if (i + 3 < 9) {
#pragma unroll
                for (int q = 0; q < 8; q++) sb[sl][q] = spr[(i + 3) * 64 + q];
            }
            s = dpp_add<0x111>(s);
            s = dpp_add<0x112>(s);
            s = dpp_add<0x114>(s);
            if (kgs == 7) gsum[192 + rg * 9 + i] = s;
        }
        __syncthreads();  // B1: gsum ready

        // ---- gate stage (threads 0..255): j = tid ----
        if (isGate) {
            float gr = gxr, gz = gxz, gn = gxn;
#pragma unroll
            for (int c = 0; c < 10; c++) {
                float tv = tfl[c];
                gr = fmaf(tv, wtfL[c * 256 + tid], gr);
                gz = fmaf(tv, wtfL[(10 + c) * 256 + tid], gz);
                gn = fmaf(tv, wtfL[(20 + c) * 256 + tid], gn);
            }
            float ar = gsum[tid] + bh0;
            float az = gsum[tid + 256] + bh1;
            float an = gsum[tid + 512] + bh2;
            float r = 1.0f / (1.0f + expf(-(gr + ar)));
            float z = 1.0f / (1.0f + expf(-(gz + az)));
            float n = tanhf(fmaf(r, an, gn));
            float hnew = (1.0f - z) * n + z * hold;
            hold = hnew;
#pragma unroll
            for (int c = 0; c < 8; c++) hq[c * 260 + tid] = hnew;
        }
        __syncthreads();  // B2: h ready

        // ---- out projection (threads 256..415) + tf update ----
        if (isProj) {
            // copy index seg>>1: banks (4*(seg>>1) + 16*(seg&1)) are exactly 2-way (free)
            const float* hp = &hq[(seg >> 1) * 260 + seg * 16];
            const float* wfp = &WfL[oc * 256 + seg * 16];
            float s = 0.f;
#pragma unroll
            for (int i = 0; i < 16; i++) s = fmaf(wfp[i], hp[i], s);
            s = dpp_add<0x111>(s);
            s = dpp_add<0x112>(s);
            s = dpp_add<0x114>(s);
            s = dpp_add<0x118>(s);   // lane seg==15 holds full sum
            if (isWr) {
                float o = s + bfc;
                out[((long)b * 1024 + t) * 10 + oc] = o;
                float pred = (o > 0.f) ? 1.f : 0.f;
                tfl[oc] = fmv ? tgt : pred;
            }
        }
        // no 3rd barrier needed: hq consumed next step only after writers passed B2;
        // gsum/tfl hazards separated by B1/B2 (racers can't pass a barrier until readers arrive).
    }
}

extern "C" void kernel_launch(void* const* d_in, const int* in_sizes, int n_in,
                              void* d_out, int out_size, void* d_ws, size_t ws_size,
                              hipStream_t stream) {
    (void)in_sizes; (void)n_in; (void)out_size; (void)ws_size;
    const float* features = (const float*)d_in[0];
    const float* targets  = (const float*)d_in[1];
    const unsigned char* fmask = (const unsigned char*)d_in[2];
    const float* W1  = (const float*)d_in[3];
    const float* b1  = (const float*)d_in[4];
    const float* g1  = (const float*)d_in[5];
    const float* be1 = (const float*)d_in[6];
    const float* m1  = (const float*)d_in[7];
    const float* v1  = (const float*)d_in[8];
    const float* W2  = (const float*)d_in[9];
    const float* b2  = (const float*)d_in[10];
    const float* g2  = (const float*)d_in[11];
    const float* be2 = (const float*)d_in[12];
    const float* m2  = (const float*)d_in[13];
    const float* v2  = (const float*)d_in[14];
    const float* W3  = (const float*)d_in[15];
    const float* b3  = (const float*)d_in[16];
    const float* g3  = (const float*)d_in[17];
    const float* be3 = (const float*)d_in[18];
    const float* m3  = (const float*)d_in[19];
    const float* v3  = (const float*)d_in[20];
    const float* Wih = (const float*)d_in[21];
    const float* Whh = (const float*)d_in[22];
    const float* bih = (const float*)d_in[23];
    const float* bhh = (const float*)d_in[24];
    const float* Wf  = (const float*)d_in[25];
    const float* bf  = (const float*)d_in[26];

    char* w = (char*)d_ws;
    float* WxT = (float*)(w + 786432);                  // 393216 B
    float* W2T = (float*)(w + 1179648);                 // 1638400 B
    float* W3T = (float*)(w + 2818048);                 // 1638400 B
    int*   flag = (int*)(w + 4456448);                  // 512 B slot
    float* X1  = (float*)(w + 4456960);                 // 128 MB; reused as Gx after conv2
    float* Gx  = X1;
    float* X2  = (float*)(w + 4456960 + 134217728);     // 32 MB
    float* F   = (float*)(w + 4456960 + 134217728 + 33554432); // 16 MB
    float* out = (float*)d_out;

    k_prep<<<1600, 256, 0, stream>>>(Wih, W2, W3, fmask, WxT, W2T, W3T, flag);
    k_conv1<<<8192, 256, 0, stream>>>(features, W1, b1, g1, be1, m1, v1, X1);
    k_conv2<<<4096, 256, 0, stream>>>(X1, W2T, b2, g2, be2, m2, v2, X2);
    k_conv3<<<4096, 256, 0, stream>>>(X2, W3T, b3, g3, be3, m3, v3, F);
    k_gemm<<<1536, 256, 0, stream>>>(F, WxT, bih, Gx);
    k_gru<<<32, 512, 0, stream>>>(Whh, Gx, Wih, bhh, Wf, bf, targets, fmask, flag, out);
}

// Round 5
// 17687.392 us; speedup vs baseline: 1.2050x; 1.0268x over previous
//
#include <hip/hip_runtime.h>
#include <math.h>

#define EPSF 1e-5f

// DPP helper: v += value from lane (i - N) within the 16-lane DPP row (0 if OOB)
template<int CTRL>
__device__ __forceinline__ float dpp_add(float v) {
    int s = __builtin_amdgcn_update_dpp(0, __float_as_int(v), CTRL, 0xf, 0xf, true);
    return v + __int_as_float(s);
}

// ---------------- prep: weight transposes + bool-dtype detect ----------------
__global__ __launch_bounds__(256) void k_prep(
    const float* __restrict__ Wih,
    const float* __restrict__ W2, const float* __restrict__ W3,
    const unsigned char* __restrict__ fmask,
    float* __restrict__ WxT,
    float* __restrict__ W2T, float* __restrict__ W3T, int* __restrict__ flag)
{
    int idx = blockIdx.x * 256 + threadIdx.x;
    if (idx < 105984) {                 // Wih[768][138] x-part -> WxT[128][768]
        int j = idx / 138, k = idx % 138;
        if (k < 128) WxT[k * 768 + j] = Wih[idx];
    }
    if (idx < 409600) {                 // W[co][ci][5][5] -> WT[tap][ci][co]
        int co = idx / 3200, r = idx % 3200;
        int ci = r / 25, tap = r % 25;
        int dst = (tap * 128 + ci) * 128 + co;
        W2T[dst] = W2[idx];
        W3T[dst] = W3[idx];
    }
    if (idx == 0) {                     // bool stored as int32? bytes 1,2,3 of each word all zero
        int nz = 0;
        for (int i = 0; i < 4096; i++) if ((i & 3) != 0) nz |= fmask[i];
        *flag = nz ? 0 : 1;
    }
}

// ---------------- conv1: [32,1,1024,40] -> X1[b][t][m1(8)][co(128)] ----------------
__global__ __launch_bounds__(256) void k_conv1(
    const float* __restrict__ X, const float* __restrict__ W1,
    const float* __restrict__ bb, const float* __restrict__ gg,
    const float* __restrict__ be, const float* __restrict__ mm_,
    const float* __restrict__ vv, float* __restrict__ X1)
{
    __shared__ __align__(16) float xs[8][44];
    __shared__ __align__(16) float ws[25][128];
    __shared__ float sc[128], sh[128];
    int bid = blockIdx.x;
    int b = bid >> 8, t0 = (bid & 255) << 2;
    int tid = threadIdx.x;
    for (int e = tid; e < 8 * 44; e += 256) {
        int tt = e / 44, mm = e % 44;
        int gt = t0 + tt - 2, gm = mm - 2;
        float val = 0.f;
        if (gt >= 0 && gt < 1024 && gm >= 0 && gm < 40)
            val = X[(b * 1024 + gt) * 40 + gm];
        xs[tt][mm] = val;
    }
    for (int e = tid; e < 3200; e += 256) {
        int tap = e >> 7, co = e & 127;
        ws[tap][co] = W1[co * 25 + tap];
    }
    if (tid < 128) {
        float s = gg[tid] / sqrtf(vv[tid] + EPSF);
        sc[tid] = s;
        sh[tid] = (bb[tid] - mm_[tid]) * s + be[tid];
    }
    __syncthreads();
    int cog = tid >> 5;          // 8 groups x 16 co
    int m1i = (tid >> 2) & 7;    // pooled mel
    int tp  = tid & 3;           // t'
    int co0 = cog * 16;
    float val[5][16];
#pragma unroll
    for (int p = 0; p < 5; p++)
#pragma unroll
        for (int i = 0; i < 16; i++) val[p][i] = 0.f;
#pragma unroll
    for (int dt = 0; dt < 5; dt++) {
#pragma unroll
        for (int dm = 0; dm < 5; dm++) {
            float w[16];
#pragma unroll
            for (int i = 0; i < 16; i += 4)
                *(float4*)&w[i] = *(const float4*)&ws[dt * 5 + dm][co0 + i];
#pragma unroll
            for (int p = 0; p < 5; p++) {
                float x = xs[tp + dt][m1i * 5 + p + dm];
#pragma unroll
                for (int i = 0; i < 16; i++) val[p][i] = fmaf(x, w[i], val[p][i]);
            }
        }
    }
    float outv[16];
#pragma unroll
    for (int i = 0; i < 16; i++) {
        float s = sc[co0 + i], h = sh[co0 + i];
        float mx = 0.f;
#pragma unroll
        for (int p = 0; p < 5; p++) {
            float y = fmaf(val[p][i], s, h);
            y = fmaxf(y, 0.f);
            mx = fmaxf(mx, y);
        }
        outv[i] = mx;
    }
    float* dst = &X1[(((long)(b * 1024 + t0 + tp)) * 8 + m1i) * 128 + co0];
#pragma unroll
    for (int i = 0; i < 16; i += 4) *(float4*)&dst[i] = *(float4*)&outv[i];
}

// ---------------- conv2: X1 -> X2[b][t][m2(2)][co(128)] ----------------
__global__ __launch_bounds__(256) void k_conv2(
    const float* __restrict__ X1, const float* __restrict__ W2T,
    const float* __restrict__ bb, const float* __restrict__ gg,
    const float* __restrict__ be, const float* __restrict__ mm_,
    const float* __restrict__ vv, float* __restrict__ X2)
{
    __shared__ __align__(16) float xs[20][33][12];  // [t''][ci(pad)][m']
    __shared__ __align__(16) float ws[5][32][64];   // [dm][ci][co]
    __shared__ float sc[64], sh[64];
    int bid = blockIdx.x;
    int coh = bid & 1, t0 = ((bid >> 1) & 63) << 4, b = bid >> 7;
    int co_base = coh * 64;
    int tid = threadIdx.x;
    int tp = tid & 15, cog = tid >> 4;   // 16 t' x 16 cog(4 co each)
    if (tid < 64) {
        int co = co_base + tid;
        float s = gg[co] / sqrtf(vv[co] + EPSF);
        sc[tid] = s;
        sh[tid] = (bb[co] - mm_[co]) * s + be[co];
    }
    float acc[4][8];
#pragma unroll
    for (int c = 0; c < 4; c++)
#pragma unroll
        for (int m = 0; m < 8; m++) acc[c][m] = 0.f;

    for (int cc = 0; cc < 4; cc++) {
        __syncthreads();
        for (int e = tid; e < 20 * 32 * 12; e += 256) {
            int ci = e & 31, mm = (e >> 5) % 12, tt = e / 384;
            int gt = t0 + tt - 2, gm = mm - 2;
            float v = 0.f;
            if (gt >= 0 && gt < 1024 && gm >= 0 && gm < 8)
                v = X1[(((long)(b * 1024 + gt)) * 8 + gm) * 128 + cc * 32 + ci];
            xs[tt][ci][mm] = v;
        }
        for (int dt = 0; dt < 5; dt++) {
            __syncthreads();
            for (int e = tid; e < 5 * 32 * 64; e += 256) {
                int co = e & 63, ci = (e >> 6) & 31, dm = e >> 11;
                ws[dm][ci][co] = W2T[((dt * 5 + dm) * 128 + cc * 32 + ci) * 128 + co_base + co];
            }
            __syncthreads();
            for (int ci = 0; ci < 32; ci++) {
                float x[12];
                *(float4*)&x[0] = *(const float4*)&xs[tp + dt][ci][0];
                *(float4*)&x[4] = *(const float4*)&xs[tp + dt][ci][4];
                *(float4*)&x[8] = *(const float4*)&xs[tp + dt][ci][8];
#pragma unroll
                for (int dm = 0; dm < 5; dm++) {
                    float w[4];
                    *(float4*)&w[0] = *(const float4*)&ws[dm][ci][cog * 4];
#pragma unroll
                    for (int c = 0; c < 4; c++)
#pragma unroll
                        for (int m = 0; m < 8; m++)
                            acc[c][m] = fmaf(w[c], x[m + dm], acc[c][m]);
                }
            }
        }
    }
    int t = t0 + tp;
#pragma unroll
    for (int m2 = 0; m2 < 2; m2++) {
        float4 ov;
        float* po = (float*)&ov;
#pragma unroll
        for (int c = 0; c < 4; c++) {
            float s = sc[cog * 4 + c], h = sh[cog * 4 + c];
            float mx = 0.f;
#pragma unroll
            for (int q = 0; q < 4; q++) {
                float y = fmaf(acc[c][m2 * 4 + q], s, h);
                y = fmaxf(y, 0.f);
                mx = fmaxf(mx, y);
            }
            po[c] = mx;
        }
        *(float4*)&X2[(((long)(b * 1024 + t)) * 2 + m2) * 128 + co_base + cog * 4] = ov;
    }
}

// ---------------- conv3: X2 -> F[t][b][co] (mel pooled to 1) ----------------
__global__ __launch_bounds__(256) void k_conv3(
    const float* __restrict__ X2, const float* __restrict__ W3T,
    const float* __restrict__ bb, const float* __restrict__ gg,
    const float* __restrict__ be, const float* __restrict__ mm_,
    const float* __restrict__ vv, float* __restrict__ F)
{
    __shared__ __align__(16) float xs[20][33][8];   // [t''][ci(pad)][m'] (m' 0..5 used)
    __shared__ __align__(16) float ws[5][32][64];
    __shared__ float sc[64], sh[64];
    int bid = blockIdx.x;
    int coh = bid & 1, t0 = ((bid >> 1) & 63) << 4, b = bid >> 7;
    int co_base = coh * 64;
    int tid = threadIdx.x;
    int tp = tid & 15, cog = tid >> 4;
    if (tid < 64) {
        int co = co_base + tid;
        float s = gg[co] / sqrtf(vv[co] + EPSF);
        sc[tid] = s;
        sh[tid] = (bb[co] - mm_[co]) * s + be[co];
    }
    float acc[4][2];
#pragma unroll
    for (int c = 0; c < 4; c++) { acc[c][0] = 0.f; acc[c][1] = 0.f; }

    for (int cc = 0; cc < 4; cc++) {
        __syncthreads();
        for (int e = tid; e < 20 * 32 * 8; e += 256) {
            int ci = e & 31, mm = (e >> 5) & 7, tt = e >> 8;
            int gt = t0 + tt - 2, gm = mm - 2;
            float v = 0.f;
            if (gt >= 0 && gt < 1024 && (gm == 0 || gm == 1))
                v = X2[(((long)(b * 1024 + gt)) * 2 + gm) * 128 + cc * 32 + ci];
            xs[tt][ci][mm] = v;
        }
        for (int dt = 0; dt < 5; dt++) {
            __syncthreads();
            for (int e = tid; e < 5 * 32 * 64; e += 256) {
                int co = e & 63, ci = (e >> 6) & 31, dm = e >> 11;
                ws[dm][ci][co] = W3T[((dt * 5 + dm) * 128 + cc * 32 + ci) * 128 + co_base + co];
            }
            __syncthreads();
            for (int ci = 0; ci < 32; ci++) {
                float x[8];
                *(float4*)&x[0] = *(const float4*)&xs[tp + dt][ci][0];
                *(float4*)&x[4] = *(const float4*)&xs[tp + dt][ci][4];
#pragma unroll
                for (int dm = 0; dm < 5; dm++) {
                    float w[4];
                    *(float4*)&w[0] = *(const float4*)&ws[dm][ci][cog * 4];
#pragma unroll
                    for (int c = 0; c < 4; c++) {
                        acc[c][0] = fmaf(w[c], x[0 + dm], acc[c][0]);
                        acc[c][1] = fmaf(w[c], x[1 + dm], acc[c][1]);
                    }
                }
            }
        }
    }
    float4 ov;
    float* po = (float*)&ov;
#pragma unroll
    for (int c = 0; c < 4; c++) {
        float s = sc[cog * 4 + c], h = sh[cog * 4 + c];
        float y0 = fmaxf(fmaf(acc[c][0], s, h), 0.f);
        float y1 = fmaxf(fmaf(acc[c][1], s, h), 0.f);
        po[c] = fmaxf(y0, y1);
    }
    *(float4*)&F[((long)(t0 + tp) * 32 + b) * 128 + co_base + cog * 4] = ov;
}

// ---------------- Gx = F @ Wihx.T + bih : [32768,128]x[128,768] ----------------
__global__ __launch_bounds__(256) void k_gemm(
    const float* __restrict__ F, const float* __restrict__ WxT,
    const float* __restrict__ bih, float* __restrict__ Gx)
{
    __shared__ __align__(16) float Fs[64][33];
    __shared__ __align__(16) float Ws[32][256];
    int bid = blockIdx.x;
    int jt = bid % 3, tb0 = (bid / 3) * 64;
    int tid = threadIdx.x;
    int tx = tid & 31, ty = tid >> 5;
    float acc[8][8];
#pragma unroll
    for (int i = 0; i < 8; i++)
#pragma unroll
        for (int j = 0; j < 8; j++) acc[i][j] = 0.f;
    for (int cc = 0; cc < 4; cc++) {
        __syncthreads();
        for (int e = tid; e < 64 * 32; e += 256) {
            int ci = e & 31, i = e >> 5;
            Fs[i][ci] = F[(long)(tb0 + i) * 128 + cc * 32 + ci];
        }
        for (int e = tid; e < 32 * 256; e += 256) {
            int jj = e & 255, ci = e >> 8;
            Ws[ci][jj] = WxT[(cc * 32 + ci) * 768 + jt * 256 + jj];
        }
        __syncthreads();
        for (int ci = 0; ci < 32; ci++) {
            float a[8], w[8];
#pragma unroll
            for (int i = 0; i < 8; i++) a[i] = Fs[ty * 8 + i][ci];
            *(float4*)&w[0] = *(const float4*)&Ws[ci][tx * 8];
            *(float4*)&w[4] = *(const float4*)&Ws[ci][tx * 8 + 4];
#pragma unroll
            for (int i = 0; i < 8; i++)
#pragma unroll
                for (int j = 0; j < 8; j++) acc[i][j] = fmaf(a[i], w[j], acc[i][j]);
        }
    }
    float bj[8];
#pragma unroll
    for (int j = 0; j < 8; j++) bj[j] = bih[jt * 256 + tx * 8 + j];
#pragma unroll
    for (int i = 0; i < 8; i++) {
        float o[8];
#pragma unroll
        for (int j = 0; j < 8; j++) o[j] = acc[i][j] + bj[j];
        float* dst = &Gx[(long)(tb0 + ty * 8 + i) * 768 + jt * 256 + tx * 8];
        *(float4*)&dst[0] = *(float4*)&o[0];
        *(float4*)&dst[4] = *(float4*)&o[4];
    }
}

// ---------------- sequential GRU: 1024 thr/batch, pure L2-stream, fits 128 VGPRs -----
// Design lesson (R2-R4): this toolchain will NOT allocate >128 arch VGPRs for this
// kernel; any larger design spills to scratch (~500 cyc serialized reloads). So:
// thread (rg=tid>>4, kgs=tid&15) computes 12 rows x 16-col slice per step, streaming
// Whh from L2 via a depth-3 rotating buffer (48 regs) -- total need ~95 < 128.
// Row schedule rotated by t%12 (same rows, identical per-row arithmetic) so LLVM
// cannot LICM-hoist the loop-invariant weight loads back into 192 live regs.
// DPP row_shr 1/2/4/8 reduces the 16-lane slice; 2 barriers/step.
// amdgpu_waves_per_eu(4,4): 16 waves/CU = exactly one 1024-thr WG -> cap 128.
__global__ __attribute__((amdgpu_waves_per_eu(4, 4))) __launch_bounds__(1024) void k_gru(
    const float* __restrict__ Whh, const float* __restrict__ Gx,
    const float* __restrict__ Wih, const float* __restrict__ bhh_g,
    const float* __restrict__ Wf, const float* __restrict__ bf_g,
    const float* __restrict__ targets, const unsigned char* __restrict__ fmask,
    const int* __restrict__ flag, float* __restrict__ out)
{
    __shared__ __align__(16) float hq[8 * 268];   // 8 copies of h[256], pad 268 (bank-stagger 12)
    __shared__ float gsum[768];
    __shared__ float tfl[16];
    __shared__ float wtfL[30 * 256];              // [g*10+c][j]
    __shared__ float WfL[2560];                   // [oc][256]
    const int b = blockIdx.x, tid = threadIdx.x;
    const int kgs = tid & 15, rg = tid >> 4;      // rg in [0,64): rows rg*12..+12, cols kgs*16..+16

    const bool isGate = (tid < 256);
    float bh0 = 0.f, bh1 = 0.f, bh2 = 0.f, hold = 0.f;
    if (isGate) { bh0 = bhh_g[tid]; bh1 = bhh_g[tid + 256]; bh2 = bhh_g[tid + 512]; }
    const bool isProj = (tid >= 256 && tid < 416);
    const int oc = (tid - 256) >> 4, seg = tid & 15;
    float bfc = isProj ? bf_g[oc] : 0.f;
    const bool isWr = isProj && (seg == 15);
    const int int32mode = flag[0];

    for (int e = tid; e < 7680; e += 1024) {      // wtf -> LDS
        int cp = e >> 8, jj = e & 255;
        int g = cp / 10, c = cp - g * 10;
        wtfL[e] = Wih[(g * 256 + jj) * 138 + 128 + c];
    }
    for (int e = tid; e < 2560; e += 1024) WfL[e] = Wf[e];
    for (int e = tid; e < 8 * 268; e += 1024) hq[e] = 0.f;
    if (tid < 16) tfl[tid] = 0.f;
    __syncthreads();

    // h slice read: copy kgs>>1, word (kgs>>1)*268 + kgs*16 -> banks 12m+16e: 2-way (free)
    const float4* hbase = (const float4*)&hq[(kgs >> 1) * 268 + kgs * 16];
    const float4* wbase = ((const float4*)Whh) + kgs * 4;   // + row*64 + q

    int tr = 0;   // t % 12, maintained incrementally
    for (int t = 0; t < 1024; t++) {
        // ---- prefetch step inputs (consumed after B1/B2) ----
        float gxr = 0.f, gxz = 0.f, gxn = 0.f;
        if (isGate) {
            const float* gx = &Gx[((long)t * 32 + b) * 768];
            gxr = gx[tid]; gxz = gx[tid + 256]; gxn = gx[tid + 512];
        }
        float tgt = 0.f; int fmv = 0;
        if (isWr) {
            tgt = targets[((long)b * 1024 + t) * 10 + oc];
            fmv = int32mode ? ((const int*)fmask)[t * 32 + b] : (int)fmask[t * 32 + b];
        }

        // ---- h fragment (4x ds_read_b128, ~2-way banks = free) ----
        float4 hv[4];
#pragma unroll
        for (int q = 0; q < 4; q++) hv[q] = hbase[q];

        // ---- preload 3 rows (rotated schedule) ----
        float4 sb[3][4];
#pragma unroll
        for (int p = 0; p < 3; p++) {
            int ro = tr + p; if (ro >= 12) ro -= 12;
            const float4* wp = wbase + (rg * 12 + ro) * 64;
#pragma unroll
            for (int q = 0; q < 4; q++) sb[p][q] = wp[q];
        }

        // ---- 12 rows, depth-3 rotation ----
#pragma unroll
        for (int i = 0; i < 12; i++) {
            const int sl = i % 3;
            int ro = tr + i; if (ro >= 12) ro -= 12;
            float s = 0.f;
#pragma unroll
            for (int q = 0; q < 4; q++) {
                s = fmaf(sb[sl][q].x, hv[q].x, s);
                s = fmaf(sb[sl][q].y, hv[q].y, s);
                s = fmaf(sb[sl][q].z, hv[q].z, s);
                s = fmaf(sb[sl][q].w, hv[q].w, s);
            }
            if (i + 3 < 12) {
                int rn = tr + i + 3; if (rn >= 12) rn -= 12;
                const float4* wp = wbase + (rg * 12 + rn) * 64;
#pragma unroll
                for (int q = 0; q < 4; q++) sb[sl][q] = wp[q];
            }
            s = dpp_add<0x111>(s);   // + lane-1
            s = dpp_add<0x112>(s);   // + lane-2
            s = dpp_add<0x114>(s);   // + lane-4
            s = dpp_add<0x118>(s);   // + lane-8 : lane kgs==15 holds full row dot
            if (kgs == 15) gsum[rg * 12 + ro] = s;
        }
        __syncthreads();  // B1: gsum ready

        // ---- gate stage (threads 0..255): j = tid ----
        if (isGate) {
            float gr = gxr, gz = gxz, gn = gxn;
#pragma unroll
            for (int c = 0; c < 10; c++) {
                float tv = tfl[c];
                gr = fmaf(tv, wtfL[c * 256 + tid], gr);
                gz = fmaf(tv, wtfL[(10 + c) * 256 + tid], gz);
                gn = fmaf(tv, wtfL[(20 + c) * 256 + tid], gn);
            }
            float ar = gsum[tid] + bh0;
            float az = gsum[tid + 256] + bh1;
            float an = gsum[tid + 512] + bh2;
            float r = 1.0f / (1.0f + expf(-(gr + ar)));
            float z = 1.0f / (1.0f + expf(-(gz + az)));
            float n = tanhf(fmaf(r, an, gn));
            float hnew = (1.0f - z) * n + z * hold;
            hold = hnew;
#pragma unroll
            for (int c = 0; c < 8; c++) hq[c * 268 + tid] = hnew;
        }
        __syncthreads();  // B2: h ready

        // ---- out projection (threads 256..415) + tf update ----
        if (isProj) {
            const float* hp = &hq[(seg >> 1) * 268 + seg * 16];
            const float* wfp = &WfL[oc * 256 + seg * 16];
            float s = 0.f;
#pragma unroll
            for (int i = 0; i < 16; i++) s = fmaf(wfp[i], hp[i], s);
            s = dpp_add<0x111>(s);
            s = dpp_add<0x112>(s);
            s = dpp_add<0x114>(s);
            s = dpp_add<0x118>(s);   // lane seg==15 holds full sum
            if (isWr) {
                float o = s + bfc;
                out[((long)b * 1024 + t) * 10 + oc] = o;
                float pred = (o > 0.f) ? 1.f : 0.f;
                tfl[oc] = fmv ? tgt : pred;
            }
        }
        // no 3rd barrier: hq consumed next step only after writers passed B2;
        // gsum/tfl hazards separated by B1/B2.
        tr++; if (tr == 12) tr = 0;
    }
}

extern "C" void kernel_launch(void* const* d_in, const int* in_sizes, int n_in,
                              void* d_out, int out_size, void* d_ws, size_t ws_size,
                              hipStream_t stream) {
    (void)in_sizes; (void)n_in; (void)out_size; (void)ws_size;
    const float* features = (const float*)d_in[0];
    const float* targets  = (const float*)d_in[1];
    const unsigned char* fmask = (const unsigned char*)d_in[2];
    const float* W1  = (const float*)d_in[3];
    const float* b1  = (const float*)d_in[4];
    const float* g1  = (const float*)d_in[5];
    const float* be1 = (const float*)d_in[6];
    const float* m1  = (const float*)d_in[7];
    const float* v1  = (const float*)d_in[8];
    const float* W2  = (const float*)d_in[9];
    const float* b2  = (const float*)d_in[10];
    const float* g2  = (const float*)d_in[11];
    const float* be2 = (const float*)d_in[12];
    const float* m2  = (const float*)d_in[13];
    const float* v2  = (const float*)d_in[14];
    const float* W3  = (const float*)d_in[15];
    const float* b3  = (const float*)d_in[16];
    const float* g3  = (const float*)d_in[17];
    const float* be3 = (const float*)d_in[18];
    const float* m3  = (const float*)d_in[19];
    const float* v3  = (const float*)d_in[20];
    const float* Wih = (const float*)d_in[21];
    const float* Whh = (const float*)d_in[22];
    const float* bih = (const float*)d_in[23];
    const float* bhh = (const float*)d_in[24];
    const float* Wf  = (const float*)d_in[25];
    const float* bf  = (const float*)d_in[26];

    char* w = (char*)d_ws;
    float* WxT = (float*)(w + 786432);                  // 393216 B
    float* W2T = (float*)(w + 1179648);                 // 1638400 B
    float* W3T = (float*)(w + 2818048);                 // 1638400 B
    int*   flag = (int*)(w + 4456448);                  // 512 B slot
    float* X1  = (float*)(w + 4456960);                 // 128 MB; reused as Gx after conv2
    float* Gx  = X1;
    float* X2  = (float*)(w + 4456960 + 134217728);     // 32 MB
    float* F   = (float*)(w + 4456960 + 134217728 + 33554432); // 16 MB
    float* out = (float*)d_out;

    k_prep<<<1600, 256, 0, stream>>>(Wih, W2, W3, fmask, WxT, W2T, W3T, flag);
    k_conv1<<<8192, 256, 0, stream>>>(features, W1, b1, g1, be1, m1, v1, X1);
    k_conv2<<<4096, 256, 0, stream>>>(X1, W2T, b2, g2, be2, m2, v2, X2);
    k_conv3<<<4096, 256, 0, stream>>>(X2, W3T, b3, g3, be3, m3, v3, F);
    k_gemm<<<1536, 256, 0, stream>>>(F, WxT, bih, Gx);
    k_gru<<<32, 1024, 0, stream>>>(Whh, Gx, Wih, bhh, Wf, bf, targets, fmask, flag, out);
}